// Round 7
// baseline (284.105 us; speedup 1.0000x reference)
//
#include <hip/hip_runtime.h>

#define N_NODES 8192
#define IN_F    1024
#define OUT_F   512
#define N_EDGES 262144
#define STRIDE  96                // fixed adjacency row stride; P(deg>=96) ~ 1e-18

// !!! INSTRUMENTATION ROUND: gemm body repeated 4x, aggregate body 5x (both
// idempotent) so each clears the ~43us top-5 threshold and returns full PMC
// rows.  Revert REP_* to 1 next round.
#define REP_GEMM 4
#define REP_AGG  5

// ---------------- workspace layout (bytes) ----------------
#define HID_OFF     0u            // 8192*512*2   =  8,388,608  (bf16 H)
#define XB_OFF      8388608u      // 8192*1024*2  = 16,777,216  (bf16 X)
#define WB_OFF      25165824u     // 512*1024*2   =  1,048,576  (bf16 W, contiguous after Xb)
#define DEG_OFF     26214400u     // 8192*4 = 32,768
#define COL_OFF     26247168u     // 8192*96*4 = 3,145,728 -> ends 29,392,896
#define UCNT_OFF    29392896u     // 8192*4 = 32,768
#define UCOL_OFF    29425664u     // 8192*96*4 = 3,145,728 -> ends 32,571,392
#define MAX_DEG     STRIDE

typedef short  bf16x8 __attribute__((ext_vector_type(8)));
typedef float  f32x4  __attribute__((ext_vector_type(4)));
typedef float  f32x2  __attribute__((ext_vector_type(2)));   // true ext-vector: OK for nontemporal builtins

__device__ __forceinline__ unsigned short f2bf(float f) {
    unsigned u = __float_as_uint(f);
    u += 0x7fffu + ((u >> 16) & 1u);   // round-to-nearest-even
    return (unsigned short)(u >> 16);
}

__device__ __forceinline__ float bflo(unsigned u) { return __uint_as_float(u << 16); }
__device__ __forceinline__ float bfhi(unsigned u) { return __uint_as_float(u & 0xffff0000u); }

__device__ __forceinline__ void ld_lds16(const void* g, void* l) {
    __builtin_amdgcn_global_load_lds(
        (const __attribute__((address_space(1))) void*)g,
        (__attribute__((address_space(3))) void*)l, 16, 0, 0);
}

// --- fp32 -> bf16 for X and W in one launch; first 8192 threads zero deg ---
#define NX8 (N_NODES * IN_F / 8)          // 1,048,576 chunks of 8
#define NW8 (OUT_F * IN_F / 8)            //    65,536
__global__ __launch_bounds__(256) void cvt_bf16_all(const float* __restrict__ x,
                                                    const float* __restrict__ w,
                                                    unsigned short* __restrict__ xb,
                                                    int* __restrict__ deg) {
    int i = blockIdx.x * blockDim.x + threadIdx.x;
    if (i < N_NODES) deg[i] = 0;
    if (i >= NX8 + NW8) return;
    const f32x4* p = (i < NX8) ? ((const f32x4*)x + (size_t)i * 2)
                               : ((const f32x4*)w + (size_t)(i - NX8) * 2);
    f32x4 v0 = __builtin_nontemporal_load(p);      // x/w not re-read as fp32
    f32x4 v1 = __builtin_nontemporal_load(p + 1);
    uint4 o;
    o.x = (unsigned)f2bf(v0.x) | ((unsigned)f2bf(v0.y) << 16);
    o.y = (unsigned)f2bf(v0.z) | ((unsigned)f2bf(v0.w) << 16);
    o.z = (unsigned)f2bf(v1.x) | ((unsigned)f2bf(v1.y) << 16);
    o.w = (unsigned)f2bf(v1.z) | ((unsigned)f2bf(v1.w) << 16);
    *((uint4*)xb + i) = o;
}

// ------- fused: MFMA GEMM (blocks 0..511) + edge scatter (512..1535) -----
// GEMM: 128x64 tile, BK=64 (16 iters), 4 waves (2m x 2n), wave = 64x32 out.
// Double-buffered LDS, ONE barrier per K-step.  LDS XOR-swizzle as before.
// INSTRUMENTED: GEMM body repeats REP_GEMM times (idempotent rewrite of H);
// scatter branch runs once (atomics not idempotent).
#define GEMM_BLOCKS 512

__global__ __launch_bounds__(256, 2) void gemm_scatter(const unsigned short* __restrict__ Xb,
                                                       const unsigned short* __restrict__ Wb,
                                                       const float* __restrict__ bias,
                                                       unsigned short* __restrict__ H,
                                                       const int* __restrict__ src,
                                                       const int* __restrict__ dst,
                                                       int* __restrict__ deg,
                                                       int* __restrict__ col) {
    __shared__ unsigned short As[2][128 * 64];   // 32 KB
    __shared__ unsigned short Bs[2][64 * 64];    // 16 KB

    const int bid = blockIdx.x;
    const int tid = threadIdx.x;

    if (bid >= GEMM_BLOCKS) {                 // ---- scatter part (runs once) ----
        int e = (bid - GEMM_BLOCKS) * 256 + tid;   // 1024*256 == N_EDGES exactly
        int s = src[e];
        int slot = atomicAdd(&deg[s], 1);
        if (slot < STRIDE) col[s * STRIDE + slot] = dst[e];
        return;
    }

    // ---- GEMM part ----
    const int lane = tid & 63;
    const int wave = tid >> 6;
    const int row0 = (bid & 63) * 128;        // 64 row-tiles
    const int col0 = (bid >> 6) * 64;         // 8 col-tiles
    const int wm   = (wave & 1) * 64;
    const int wn   = (wave >> 1) * 32;
    const int fm   = lane & 15;
    const int fm7  = fm & 7;
    const int q    = lane >> 4;               // k-quad within the 32-k MFMA window

    // staging: slot = tid covers (r = tid>>3, swizzled k-chunk); +256 -> r+32, ...
    const int r0 = tid >> 3;                              // 0..31
    const int kp = ((tid & 7) ^ (r0 & 7)) * 8;            // swizzled k elem-offset
    const unsigned short* Xbase = Xb + (size_t)(row0 + r0) * IN_F + kp;
    const unsigned short* Wbase = Wb + (size_t)(col0 + r0) * IN_F + kp;

#define STAGE(buf, k0) do {                                                   \
    ld_lds16(Xbase            + (k0), &As[buf][tid * 8]);                     \
    ld_lds16(Xbase + 32*IN_F  + (k0), &As[buf][(tid + 256) * 8]);             \
    ld_lds16(Xbase + 64*IN_F  + (k0), &As[buf][(tid + 512) * 8]);             \
    ld_lds16(Xbase + 96*IN_F  + (k0), &As[buf][(tid + 768) * 8]);             \
    ld_lds16(Wbase            + (k0), &Bs[buf][tid * 8]);                     \
    ld_lds16(Wbase + 32*IN_F  + (k0), &Bs[buf][(tid + 256) * 8]);             \
} while (0)

#define COMPUTE(buf) do {                                                     \
    _Pragma("unroll")                                                         \
    for (int s = 0; s < 2; ++s) {                                             \
        const int kq = s * 4 + q;                                             \
        bf16x8 a[2 + 2], b[2];                                                \
        _Pragma("unroll")                                                     \
        for (int mi = 0; mi < 4; ++mi)                                        \
            a[mi] = *(const bf16x8*)&As[buf][(((wm + mi*16 + fm) << 3) + (kq ^ fm7)) << 3]; \
        _Pragma("unroll")                                                     \
        for (int ni = 0; ni < 2; ++ni)                                        \
            b[ni] = *(const bf16x8*)&Bs[buf][(((wn + ni*16 + fm) << 3) + (kq ^ fm7)) << 3]; \
        _Pragma("unroll")                                                     \
        for (int mi = 0; mi < 4; ++mi)                                        \
            _Pragma("unroll")                                                 \
            for (int ni = 0; ni < 2; ++ni)                                    \
                acc[mi][ni] = __builtin_amdgcn_mfma_f32_16x16x32_bf16(        \
                    a[mi], b[ni], acc[mi][ni], 0, 0, 0);                      \
    }                                                                         \
} while (0)

    for (int rep = 0; rep < REP_GEMM; ++rep) {
        asm volatile("" ::: "memory");            // forbid cross-rep collapsing

        f32x4 acc[4][2];
#pragma unroll
        for (int i = 0; i < 4; ++i)
#pragma unroll
            for (int j = 0; j < 2; ++j) acc[i][j] = (f32x4)0.f;

        STAGE(0, 0);
        __syncthreads();                          // drain prologue stage
        int cur = 0;
        for (int t = 0; t < 15; ++t) {
            STAGE(cur ^ 1, (t + 1) * 64);         // prefetch next K-tile (other buffer)
            COMPUTE(cur);                         // MFMA on current tile overlaps the loads
            __syncthreads();                      // one barrier/K-step: drains vmcnt + sync
            cur ^= 1;
        }
        COMPUTE(cur);                             // last tile, nothing left to stage

        const int cm = (lane >> 4) * 4;   // C/D: col = lane&15, row = (lane>>4)*4 + reg
#pragma unroll
        for (int ni = 0; ni < 2; ++ni) {
            const int c = col0 + wn + ni * 16 + fm;
            const float bv = bias[c];
#pragma unroll
            for (int mi = 0; mi < 4; ++mi) {
#pragma unroll
                for (int r = 0; r < 4; ++r) {
                    const int row = row0 + wm + mi * 16 + cm + r;
                    H[(size_t)row * OUT_F + c] = f2bf(acc[mi][ni][r] + bv);
                }
            }
        }
        __syncthreads();                          // LDS safe to restage next rep
    }
#undef STAGE
#undef COMPUTE
}

// ---- dedup: wave per node -> compacted unique-neighbor list (ucol, ucnt) ----
__global__ __launch_bounds__(256) void dedup(const int* __restrict__ dg,
                                             const int* __restrict__ col,
                                             int* __restrict__ ucol,
                                             int* __restrict__ ucnt) {
    __shared__ int nbr[4][MAX_DEG];
    __shared__ int wcnt[4];
    const int wave = threadIdx.x >> 6;
    const int lane = threadIdx.x & 63;
    const int v    = blockIdx.x * 4 + wave;
    int d = dg[v];
    if (d > MAX_DEG) d = MAX_DEG;

    if (lane == 0) wcnt[wave] = 0;
    int id0 = -1, id1 = -1;
    if (lane < d)      { id0 = col[v * STRIDE + lane];      nbr[wave][lane]      = id0; }
    if (64 + lane < d) { id1 = col[v * STRIDE + 64 + lane]; nbr[wave][64 + lane] = id1; }
    __builtin_amdgcn_wave_barrier();   // wave-synchronous LDS hand-off

    // keep entry i iff no j<i equals it (no early exit -> LDS reads pipeline)
    bool k0 = (lane < d);
    const int lim0 = k0 ? lane : 0;
    for (int j = 0; j < lim0; ++j) k0 = k0 & (nbr[wave][j] != id0);
    bool k1 = (64 + lane < d);
    const int lim1 = k1 ? (64 + lane) : 0;
    for (int j = 0; j < lim1; ++j) k1 = k1 & (nbr[wave][j] != id1);
    if (k0) ucol[v * STRIDE + atomicAdd(&wcnt[wave], 1)] = id0;
    if (k1) ucol[v * STRIDE + atomicAdd(&wcnt[wave], 1)] = id1;
    __builtin_amdgcn_wave_barrier();
    if (lane == 0) ucnt[v] = wcnt[wave];
}

// ---- aggregate: wave per (node, feature-QUARTER), XCD-routed quarters. ----
// INSTRUMENTED: whole body repeats REP_AGG times (idempotent rewrite of out).
// The per-rep FETCH_SIZE in the PMC row tells whether the H gather is
// L2/L3-resident (~40 MB/rep incl. ucol) or HBM-thrashing (~270 MB/rep).
__global__ __launch_bounds__(256, 8) void aggregate(const unsigned short* __restrict__ H,
                                                    const int* __restrict__ ucnt,
                                                    const int* __restrict__ ucol,
                                                    float* __restrict__ out) {
    const int wave = threadIdx.x >> 6;
    const int lane = threadIdx.x & 63;
    const int bid  = blockIdx.x;
    const int q    = bid & 3;                 // feature quarter; == XCD pair {q,q+4}
    const int v    = (bid >> 2) * 4 + wave;   // node (bijective over 8192 blocks)
    const int* uq  = ucol + v * STRIDE;
    // lane covers 2 feats (4 B) of quarter q: 64 lanes x 4 B = 256 B/row segment
    const unsigned short* Hq = H + q * 128 + lane * 2;

    for (int rep = 0; rep < REP_AGG; ++rep) {
        asm volatile("" ::: "memory");            // forbid cross-rep collapsing
        const int n = ucnt[v];

        float a0 = 0.f, a1 = 0.f;
        int e = 0;
        for (; e + 16 <= n; e += 16) {            // 16 rows in flight
            unsigned h[16];
#pragma unroll
            for (int t = 0; t < 16; ++t)
                h[t] = *(const unsigned*)&Hq[(size_t)uq[e + t] * OUT_F];
#pragma unroll
            for (int t = 0; t < 16; ++t) { a0 += bflo(h[t]); a1 += bfhi(h[t]); }
        }
        for (; e + 4 <= n; e += 4) {
            unsigned h[4];
#pragma unroll
            for (int t = 0; t < 4; ++t)
                h[t] = *(const unsigned*)&Hq[(size_t)uq[e + t] * OUT_F];
#pragma unroll
            for (int t = 0; t < 4; ++t) { a0 += bflo(h[t]); a1 += bfhi(h[t]); }
        }
        for (; e < n; ++e) {
            unsigned h = *(const unsigned*)&Hq[(size_t)uq[e] * OUT_F];
            a0 += bflo(h); a1 += bfhi(h);
        }
        f32x2 o = {fmaxf(a0, 0.f), fmaxf(a1, 0.f)};
        // 64 lanes x 8 B = 512 B contiguous per (node, quarter); never re-read
        __builtin_nontemporal_store(o, (f32x2*)&out[(size_t)v * OUT_F + q * 128 + lane * 2]);
    }
}

extern "C" void kernel_launch(void* const* d_in, const int* in_sizes, int n_in,
                              void* d_out, int out_size, void* d_ws, size_t ws_size,
                              hipStream_t stream) {
    const float* x  = (const float*)d_in[0];
    const float* W  = (const float*)d_in[1];
    const float* b  = (const float*)d_in[2];
    const int*   ei = (const int*)d_in[3];      // [2, N_EDGES]: src then dst
    float* out = (float*)d_out;

    char* ws = (char*)d_ws;
    unsigned short* H    = (unsigned short*)(ws + HID_OFF);
    unsigned short* Xb   = (unsigned short*)(ws + XB_OFF);   // Wb contiguous after
    unsigned short* Wb   = (unsigned short*)(ws + WB_OFF);
    int*            deg  = (int*)(ws + DEG_OFF);
    int*            col  = (int*)(ws + COL_OFF);
    int*            ucnt = (int*)(ws + UCNT_OFF);
    int*            ucol = (int*)(ws + UCOL_OFF);

    // 1) convert X,W to bf16 + zero deg
    cvt_bf16_all<<<(NX8 + NW8 + 255) / 256, 256, 0, stream>>>(x, W, Xb, deg);

    // 2) GEMM (512 blocks, x REP_GEMM) + edge scatter (1024 blocks) fused
    gemm_scatter<<<GEMM_BLOCKS + N_EDGES / 256, 256, 0, stream>>>(
        Xb, Wb, b, H, ei, ei + N_EDGES, deg, col);

    // 3) compact unique-neighbor lists (wave per node)
    dedup<<<N_NODES / 4, 256, 0, stream>>>(deg, col, ucol, ucnt);

    // 4) wave per (node, quarter), x REP_AGG
    aggregate<<<N_NODES * 4 / 4, 256, 0, stream>>>(H, ucnt, ucol, out);
}

// Round 8
// 141.486 us; speedup vs baseline: 2.0080x; 2.0080x over previous
//
#include <hip/hip_runtime.h>

#define N_NODES 8192
#define IN_F    1024
#define OUT_F   512
#define N_EDGES 262144
#define STRIDE  96                // fixed adjacency row stride; P(deg>=96) ~ 1e-18

// ---------------- workspace layout (bytes) ----------------
#define HID_OFF     0u            // 8192*512*2   =  8,388,608  (bf16 H)
#define XB_OFF      8388608u      // 8192*1024*2  = 16,777,216  (bf16 X)
#define WB_OFF      25165824u     // 512*1024*2   =  1,048,576  (bf16 W, contiguous after Xb)
#define DEG_OFF     26214400u     // 8192*4 = 32,768
#define COL_OFF     26247168u     // 8192*96*4 = 3,145,728 -> ends 29,392,896
#define UCNT_OFF    29392896u     // 8192*4 = 32,768
#define UCOL_OFF    29425664u     // 8192*96*4 = 3,145,728 -> ends 32,571,392
#define MAX_DEG     STRIDE

typedef short  bf16x8 __attribute__((ext_vector_type(8)));
typedef float  f32x4  __attribute__((ext_vector_type(4)));
typedef float  f32x2  __attribute__((ext_vector_type(2)));   // true ext-vector: OK for nontemporal builtins

__device__ __forceinline__ unsigned short f2bf(float f) {
    unsigned u = __float_as_uint(f);
    u += 0x7fffu + ((u >> 16) & 1u);   // round-to-nearest-even
    return (unsigned short)(u >> 16);
}

__device__ __forceinline__ float bflo(unsigned u) { return __uint_as_float(u << 16); }
__device__ __forceinline__ float bfhi(unsigned u) { return __uint_as_float(u & 0xffff0000u); }

__device__ __forceinline__ void ld_lds16(const void* g, void* l) {
    __builtin_amdgcn_global_load_lds(
        (const __attribute__((address_space(1))) void*)g,
        (__attribute__((address_space(3))) void*)l, 16, 0, 0);
}

// --- fp32 -> bf16 for X and W in one launch; first 8192 threads zero deg ---
#define NX8 (N_NODES * IN_F / 8)          // 1,048,576 chunks of 8
#define NW8 (OUT_F * IN_F / 8)            //    65,536
__global__ __launch_bounds__(256) void cvt_bf16_all(const float* __restrict__ x,
                                                    const float* __restrict__ w,
                                                    unsigned short* __restrict__ xb,
                                                    int* __restrict__ deg) {
    int i = blockIdx.x * blockDim.x + threadIdx.x;
    if (i < N_NODES) deg[i] = 0;
    if (i >= NX8 + NW8) return;
    const f32x4* p = (i < NX8) ? ((const f32x4*)x + (size_t)i * 2)
                               : ((const f32x4*)w + (size_t)(i - NX8) * 2);
    f32x4 v0 = __builtin_nontemporal_load(p);      // x/w not re-read as fp32
    f32x4 v1 = __builtin_nontemporal_load(p + 1);
    uint4 o;
    o.x = (unsigned)f2bf(v0.x) | ((unsigned)f2bf(v0.y) << 16);
    o.y = (unsigned)f2bf(v0.z) | ((unsigned)f2bf(v0.w) << 16);
    o.z = (unsigned)f2bf(v1.x) | ((unsigned)f2bf(v1.y) << 16);
    o.w = (unsigned)f2bf(v1.z) | ((unsigned)f2bf(v1.w) << 16);
    *((uint4*)xb + i) = o;
}

// ------- fused: MFMA GEMM (blocks 0..511) + edge scatter (512..1535) -----
// GEMM: 128x64 tile, BK=64 (16 iters), 4 waves (2m x 2n), wave = 64x32 out.
// R7 PMC: the old dbuf+__syncthreads structure stalled ~3900 cy/K-step
// (MfmaUtil 12.6%, occupancy 21%) because syncthreads drains vmcnt(0),
// exposing full staging latency every step.  Now: TRIPLE-buffered LDS,
// counted wait.  Per K-step: STAGE(t+1) -> s_waitcnt vmcnt(6) (only L_t
// drained; L_{t+1}'s 6 loads stay in flight across the barrier) ->
// s_barrier -> COMPUTE(t).  One barrier/step, race-free with 3 buffers:
// the buffer STAGE overwrites was last read two barriers ago.
#define GEMM_BLOCKS 512

__global__ __launch_bounds__(256, 2) void gemm_scatter(const unsigned short* __restrict__ Xb,
                                                       const unsigned short* __restrict__ Wb,
                                                       const float* __restrict__ bias,
                                                       unsigned short* __restrict__ H,
                                                       const int* __restrict__ src,
                                                       const int* __restrict__ dst,
                                                       int* __restrict__ deg,
                                                       int* __restrict__ col) {
    __shared__ unsigned short As[3][128 * 64];   // 48 KB
    __shared__ unsigned short Bs[3][64 * 64];    // 24 KB  (72 KB total: 2 blocks/CU)

    const int bid = blockIdx.x;
    const int tid = threadIdx.x;

    if (bid >= GEMM_BLOCKS) {                 // ---- scatter part ----
        int e = (bid - GEMM_BLOCKS) * 256 + tid;   // 1024*256 == N_EDGES exactly
        int s = src[e];
        int slot = atomicAdd(&deg[s], 1);
        if (slot < STRIDE) col[s * STRIDE + slot] = dst[e];
        return;
    }

    // ---- GEMM part ----
    const int lane = tid & 63;
    const int wave = tid >> 6;
    const int row0 = (bid & 63) * 128;        // 64 row-tiles
    const int col0 = (bid >> 6) * 64;         // 8 col-tiles
    const int wm   = (wave & 1) * 64;
    const int wn   = (wave >> 1) * 32;
    const int fm   = lane & 15;
    const int fm7  = fm & 7;
    const int q    = lane >> 4;               // k-quad within the 32-k MFMA window

    f32x4 acc[4][2];
#pragma unroll
    for (int i = 0; i < 4; ++i)
#pragma unroll
        for (int j = 0; j < 2; ++j) acc[i][j] = (f32x4)0.f;

    // staging: slot = tid covers (r = tid>>3, swizzled k-chunk); +256 -> r+32, ...
    const int r0 = tid >> 3;                              // 0..31
    const int kp = ((tid & 7) ^ (r0 & 7)) * 8;            // swizzled k elem-offset
    const unsigned short* Xbase = Xb + (size_t)(row0 + r0) * IN_F + kp;
    const unsigned short* Wbase = Wb + (size_t)(col0 + r0) * IN_F + kp;

#define STAGE(buf, k0) do {                                                   \
    ld_lds16(Xbase            + (k0), &As[buf][tid * 8]);                     \
    ld_lds16(Xbase + 32*IN_F  + (k0), &As[buf][(tid + 256) * 8]);             \
    ld_lds16(Xbase + 64*IN_F  + (k0), &As[buf][(tid + 512) * 8]);             \
    ld_lds16(Xbase + 96*IN_F  + (k0), &As[buf][(tid + 768) * 8]);             \
    ld_lds16(Wbase            + (k0), &Bs[buf][tid * 8]);                     \
    ld_lds16(Wbase + 32*IN_F  + (k0), &Bs[buf][(tid + 256) * 8]);             \
} while (0)

#define COMPUTE(buf) do {                                                     \
    _Pragma("unroll")                                                         \
    for (int s = 0; s < 2; ++s) {                                             \
        const int kq = s * 4 + q;                                             \
        bf16x8 a[4], b[2];                                                    \
        _Pragma("unroll")                                                     \
        for (int mi = 0; mi < 4; ++mi)                                        \
            a[mi] = *(const bf16x8*)&As[buf][(((wm + mi*16 + fm) << 3) + (kq ^ fm7)) << 3]; \
        _Pragma("unroll")                                                     \
        for (int ni = 0; ni < 2; ++ni)                                        \
            b[ni] = *(const bf16x8*)&Bs[buf][(((wn + ni*16 + fm) << 3) + (kq ^ fm7)) << 3]; \
        _Pragma("unroll")                                                     \
        for (int mi = 0; mi < 4; ++mi)                                        \
            _Pragma("unroll")                                                 \
            for (int ni = 0; ni < 2; ++ni)                                    \
                acc[mi][ni] = __builtin_amdgcn_mfma_f32_16x16x32_bf16(        \
                    a[mi], b[ni], acc[mi][ni], 0, 0, 0);                      \
    }                                                                         \
} while (0)

    STAGE(0, 0);                              // prologue: L_0 in flight
    // main loop: t = 0..14.  STAGE(t+1) -> wait L_t (vmcnt(6) leaves L_{t+1}
    // in flight) -> barrier -> COMPUTE(t).  "memory" clobbers pin the LDS
    // reads/DMA-writes on the correct side of the wait (compiler cannot see
    // the DMA->LDS dependency).
    for (int t = 0; t < 15; ++t) {
        const int cur = t % 3;
        const int nxt = (t + 1) % 3;
        STAGE(nxt, (t + 1) * 64);
        asm volatile("s_waitcnt vmcnt(6)" ::: "memory");
        __builtin_amdgcn_s_barrier();
        asm volatile("" ::: "memory");
        COMPUTE(cur);
    }
    // epilogue: drain L_15, compute it
    asm volatile("s_waitcnt vmcnt(0)" ::: "memory");
    __builtin_amdgcn_s_barrier();
    asm volatile("" ::: "memory");
    COMPUTE(15 % 3);

    const int cm = (lane >> 4) * 4;   // C/D: col = lane&15, row = (lane>>4)*4 + reg
#pragma unroll
    for (int ni = 0; ni < 2; ++ni) {
        const int c = col0 + wn + ni * 16 + fm;
        const float bv = bias[c];
#pragma unroll
        for (int mi = 0; mi < 4; ++mi) {
#pragma unroll
            for (int r = 0; r < 4; ++r) {
                const int row = row0 + wm + mi * 16 + cm + r;
                H[(size_t)row * OUT_F + c] = f2bf(acc[mi][ni][r] + bv);
            }
        }
    }
#undef STAGE
#undef COMPUTE
}

// ---- dedup: wave per node -> compacted unique-neighbor list (ucol, ucnt) ----
__global__ __launch_bounds__(256) void dedup(const int* __restrict__ dg,
                                             const int* __restrict__ col,
                                             int* __restrict__ ucol,
                                             int* __restrict__ ucnt) {
    __shared__ int nbr[4][MAX_DEG];
    __shared__ int wcnt[4];
    const int wave = threadIdx.x >> 6;
    const int lane = threadIdx.x & 63;
    const int v    = blockIdx.x * 4 + wave;
    int d = dg[v];
    if (d > MAX_DEG) d = MAX_DEG;

    if (lane == 0) wcnt[wave] = 0;
    int id0 = -1, id1 = -1;
    if (lane < d)      { id0 = col[v * STRIDE + lane];      nbr[wave][lane]      = id0; }
    if (64 + lane < d) { id1 = col[v * STRIDE + 64 + lane]; nbr[wave][64 + lane] = id1; }
    __builtin_amdgcn_wave_barrier();   // wave-synchronous LDS hand-off

    // keep entry i iff no j<i equals it (no early exit -> LDS reads pipeline)
    bool k0 = (lane < d);
    const int lim0 = k0 ? lane : 0;
    for (int j = 0; j < lim0; ++j) k0 = k0 & (nbr[wave][j] != id0);
    bool k1 = (64 + lane < d);
    const int lim1 = k1 ? (64 + lane) : 0;
    for (int j = 0; j < lim1; ++j) k1 = k1 & (nbr[wave][j] != id1);
    if (k0) ucol[v * STRIDE + atomicAdd(&wcnt[wave], 1)] = id0;
    if (k1) ucol[v * STRIDE + atomicAdd(&wcnt[wave], 1)] = id1;
    __builtin_amdgcn_wave_barrier();
    if (lane == 0) ucnt[v] = wcnt[wave];
}

// ---- aggregate: wave per (node, feature-QUARTER), XCD-routed quarters. ----
// R7 PMC: ~16 us, ~17 TB/s effective (L2/L3-served; floor ~8 us).  Kept as-is.
__global__ __launch_bounds__(256, 8) void aggregate(const unsigned short* __restrict__ H,
                                                    const int* __restrict__ ucnt,
                                                    const int* __restrict__ ucol,
                                                    float* __restrict__ out) {
    const int wave = threadIdx.x >> 6;
    const int lane = threadIdx.x & 63;
    const int bid  = blockIdx.x;
    const int q    = bid & 3;                 // feature quarter; == XCD pair {q,q+4}
    const int v    = (bid >> 2) * 4 + wave;   // node (bijective over 8192 blocks)
    const int n    = ucnt[v];
    const int* uq  = ucol + v * STRIDE;
    // lane covers 2 feats (4 B) of quarter q: 64 lanes x 4 B = 256 B/row segment
    const unsigned short* Hq = H + q * 128 + lane * 2;

    float a0 = 0.f, a1 = 0.f;
    int e = 0;
    for (; e + 16 <= n; e += 16) {            // 16 rows in flight
        unsigned h[16];
#pragma unroll
        for (int t = 0; t < 16; ++t)
            h[t] = *(const unsigned*)&Hq[(size_t)uq[e + t] * OUT_F];
#pragma unroll
        for (int t = 0; t < 16; ++t) { a0 += bflo(h[t]); a1 += bfhi(h[t]); }
    }
    for (; e + 4 <= n; e += 4) {
        unsigned h[4];
#pragma unroll
        for (int t = 0; t < 4; ++t)
            h[t] = *(const unsigned*)&Hq[(size_t)uq[e + t] * OUT_F];
#pragma unroll
        for (int t = 0; t < 4; ++t) { a0 += bflo(h[t]); a1 += bfhi(h[t]); }
    }
    for (; e < n; ++e) {
        unsigned h = *(const unsigned*)&Hq[(size_t)uq[e] * OUT_F];
        a0 += bflo(h); a1 += bfhi(h);
    }
    f32x2 o = {fmaxf(a0, 0.f), fmaxf(a1, 0.f)};
    // 64 lanes x 8 B = 512 B contiguous per (node, quarter); never re-read
    __builtin_nontemporal_store(o, (f32x2*)&out[(size_t)v * OUT_F + q * 128 + lane * 2]);
}

extern "C" void kernel_launch(void* const* d_in, const int* in_sizes, int n_in,
                              void* d_out, int out_size, void* d_ws, size_t ws_size,
                              hipStream_t stream) {
    const float* x  = (const float*)d_in[0];
    const float* W  = (const float*)d_in[1];
    const float* b  = (const float*)d_in[2];
    const int*   ei = (const int*)d_in[3];      // [2, N_EDGES]: src then dst
    float* out = (float*)d_out;

    char* ws = (char*)d_ws;
    unsigned short* H    = (unsigned short*)(ws + HID_OFF);
    unsigned short* Xb   = (unsigned short*)(ws + XB_OFF);   // Wb contiguous after
    unsigned short* Wb   = (unsigned short*)(ws + WB_OFF);
    int*            deg  = (int*)(ws + DEG_OFF);
    int*            col  = (int*)(ws + COL_OFF);
    int*            ucnt = (int*)(ws + UCNT_OFF);
    int*            ucol = (int*)(ws + UCOL_OFF);

    // 1) convert X,W to bf16 + zero deg
    cvt_bf16_all<<<(NX8 + NW8 + 255) / 256, 256, 0, stream>>>(x, W, Xb, deg);

    // 2) GEMM (512 blocks, 3-buf counted-vmcnt pipeline) + edge scatter (1024 blocks)
    gemm_scatter<<<GEMM_BLOCKS + N_EDGES / 256, 256, 0, stream>>>(
        Xb, Wb, b, H, ei, ei + N_EDGES, deg, col);

    // 3) compact unique-neighbor lists (wave per node)
    dedup<<<N_NODES / 4, 256, 0, stream>>>(deg, col, ucol, ucnt);

    // 4) wave per (node, quarter): 32768 tasks, XCD-routed, L2-resident gather
    aggregate<<<N_NODES * 4 / 4, 256, 0, stream>>>(H, ucnt, ucol, out);
}

// Round 9
// 139.981 us; speedup vs baseline: 2.0296x; 1.0108x over previous
//
#include <hip/hip_runtime.h>

#define N_NODES 8192
#define IN_F    1024
#define OUT_F   512
#define N_EDGES 262144
#define STRIDE  96                // fixed adjacency row stride; P(deg>=96) ~ 1e-18

// ---------------- workspace layout (bytes) ----------------
#define HID_OFF     0u            // 8192*512*2   =  8,388,608  (bf16 H)
#define WB_OFF      8388608u      // 512*1024*2   =  1,048,576  (bf16 W)
#define DEG_OFF     9437184u      // 8192*4 = 32,768
#define COL_OFF     9469952u      // 8192*96*4 = 3,145,728
#define UCNT_OFF    12615680u     // 8192*4 = 32,768
#define UCOL_OFF    12648448u     // 8192*96*4 = 3,145,728 -> ends 15,794,176
#define MAX_DEG     STRIDE

typedef short  bf16x8 __attribute__((ext_vector_type(8)));
typedef float  f32x4  __attribute__((ext_vector_type(4)));
typedef float  f32x2  __attribute__((ext_vector_type(2)));

__device__ __forceinline__ unsigned short f2bf(float f) {
    unsigned u = __float_as_uint(f);
    u += 0x7fffu + ((u >> 16) & 1u);   // round-to-nearest-even
    return (unsigned short)(u >> 16);
}

__device__ __forceinline__ float bflo(unsigned u) { return __uint_as_float(u << 16); }
__device__ __forceinline__ float bfhi(unsigned u) { return __uint_as_float(u & 0xffff0000u); }

__device__ __forceinline__ void ld_lds16(const void* g, void* l) {
    __builtin_amdgcn_global_load_lds(
        (const __attribute__((address_space(1))) void*)g,
        (__attribute__((address_space(3))) void*)l, 16, 0, 0);
}

// --- tiny: fp32->bf16 for W only (X is now consumed fp32 by the GEMM), zero deg ---
#define NW8 (OUT_F * IN_F / 8)            // 65,536 chunks of 8 = 256 blocks exactly
__global__ __launch_bounds__(256) void cvt_w(const float* __restrict__ w,
                                             unsigned short* __restrict__ wb,
                                             int* __restrict__ deg) {
    int i = blockIdx.x * blockDim.x + threadIdx.x;
    if (i < N_NODES) deg[i] = 0;
    const f32x4* p = (const f32x4*)w + (size_t)i * 2;
    f32x4 v0 = __builtin_nontemporal_load(p);
    f32x4 v1 = __builtin_nontemporal_load(p + 1);
    uint4 o;
    o.x = (unsigned)f2bf(v0.x) | ((unsigned)f2bf(v0.y) << 16);
    o.y = (unsigned)f2bf(v0.z) | ((unsigned)f2bf(v0.w) << 16);
    o.z = (unsigned)f2bf(v1.x) | ((unsigned)f2bf(v1.y) << 16);
    o.w = (unsigned)f2bf(v1.z) | ((unsigned)f2bf(v1.w) << 16);
    *((uint4*)wb + i) = o;
}

// ------- fused: MFMA GEMM (blocks 0..511) + edge scatter (512..1535) -----
// GEMM: 128x64 tile, BK=64 (16 iters), 4 waves (2m x 2n), wave = 64x32 out.
// NEW: A (X) is staged as FP32 straight from the input (no pre-convert pass)
// and converted to bf16 in the fragment path with v_cvt_pk_bf16_f32 (RNE —
// identical numerics to the old bf16 pre-pass).  The GEMM is stall-bound
// (R7: MfmaUtil 12.6%, VALUBusy 5.4%, ~85% idle), so the extra staged bytes
// and VALU ride in the stall shadow; in exchange the 10us cvt pass dies.
// A-LDS layout: 16B slots s=0..2047; slot s holds row r=s>>4, phys-chunk
// cperm=(s>>1)&7, half h=s&1; logical k-chunk c = cperm ^ (r&7) (XOR swizzle,
// same involution as before, now at 32B logical-chunk granularity with the
// global source address pre-swizzled so global_load_lds's slot=lane rule holds).
#define GEMM_BLOCKS 512

__global__ __launch_bounds__(256, 2) void gemm_scatter(const float* __restrict__ X,
                                                       const unsigned short* __restrict__ Wb,
                                                       const float* __restrict__ bias,
                                                       unsigned short* __restrict__ H,
                                                       const int* __restrict__ src,
                                                       const int* __restrict__ dst,
                                                       int* __restrict__ deg,
                                                       int* __restrict__ col) {
    __shared__ float          Asf[2][8192];      // 2 x 32 KB (fp32 A tile)
    __shared__ unsigned short Bs[2][64 * 64];    // 2 x  8 KB (bf16 B tile) -> 80 KB, 2 blk/CU

    const int bid = blockIdx.x;
    const int tid = threadIdx.x;

    if (bid >= GEMM_BLOCKS) {                 // ---- scatter part ----
        int e = (bid - GEMM_BLOCKS) * 256 + tid;   // 1024*256 == N_EDGES exactly
        int s = src[e];
        int slot = atomicAdd(&deg[s], 1);
        if (slot < STRIDE) col[s * STRIDE + slot] = dst[e];
        return;
    }

    // ---- GEMM part ----
    const int lane = tid & 63;
    const int wave = tid >> 6;
    const int row0 = (bid & 63) * 128;        // 64 row-tiles
    const int col0 = (bid >> 6) * 64;         // 8 col-tiles
    const int wm   = (wave & 1) * 64;
    const int wn   = (wave >> 1) * 32;
    const int fm   = lane & 15;
    const int fm7  = fm & 7;
    const int q    = lane >> 4;               // k-quad within the 32-k MFMA window

    f32x4 acc[4][2];
#pragma unroll
    for (int i = 0; i < 4; ++i)
#pragma unroll
        for (int j = 0; j < 2; ++j) acc[i][j] = (f32x4)0.f;

    // A staging: call j covers slots s = j*256+tid; r = j*16 + (tid>>4),
    // cperm = (tid>>1)&7, h = tid&1, c = cperm ^ ((tid>>4)&7)  (j-invariant).
    const int acperm = (tid >> 1) & 7;
    const int ac     = acperm ^ ((tid >> 4) & 7);
    const float* Xa  = X + (size_t)(row0 + (tid >> 4)) * IN_F + ac * 8 + (tid & 1) * 4;
    // B staging unchanged (bf16, 8-elem chunks, same XOR swizzle)
    const int r0 = tid >> 3;                              // 0..31
    const int kp = ((tid & 7) ^ (r0 & 7)) * 8;            // swizzled k elem-offset
    const unsigned short* Wbase = Wb + (size_t)(col0 + r0) * IN_F + kp;

#define STAGE(buf, k0) do {                                                   \
    _Pragma("unroll")                                                         \
    for (int j = 0; j < 8; ++j)                                               \
        ld_lds16(Xa + (size_t)j * 16 * IN_F + (k0),                           \
                 &Asf[buf][(size_t)(j * 256 + tid) * 4]);                     \
    ld_lds16(Wbase            + (k0), &Bs[buf][tid * 8]);                     \
    ld_lds16(Wbase + 32*IN_F  + (k0), &Bs[buf][(tid + 256) * 8]);             \
} while (0)

#define COMPUTE(buf) do {                                                     \
    _Pragma("unroll")                                                         \
    for (int s2 = 0; s2 < 2; ++s2) {                                          \
        const int kq = s2 * 4 + q;                                            \
        bf16x8 a[4], b[2];                                                    \
        _Pragma("unroll")                                                     \
        for (int mi = 0; mi < 4; ++mi) {                                      \
            const int rr = wm + mi * 16 + fm;                                 \
            const f32x4* pa = (const f32x4*)&Asf[buf][(size_t)(rr * 16 + ((kq ^ fm7) << 1)) * 4]; \
            f32x4 lo = pa[0], hi = pa[1];                                     \
            unsigned u0, u1, u2, u3;                                          \
            asm("v_cvt_pk_bf16_f32 %0, %1, %2" : "=v"(u0) : "v"(lo.x), "v"(lo.y)); \
            asm("v_cvt_pk_bf16_f32 %0, %1, %2" : "=v"(u1) : "v"(lo.z), "v"(lo.w)); \
            asm("v_cvt_pk_bf16_f32 %0, %1, %2" : "=v"(u2) : "v"(hi.x), "v"(hi.y)); \
            asm("v_cvt_pk_bf16_f32 %0, %1, %2" : "=v"(u3) : "v"(hi.z), "v"(hi.w)); \
            union { unsigned u[4]; bf16x8 v; } pk;                            \
            pk.u[0] = u0; pk.u[1] = u1; pk.u[2] = u2; pk.u[3] = u3;           \
            a[mi] = pk.v;                                                     \
        }                                                                     \
        _Pragma("unroll")                                                     \
        for (int ni = 0; ni < 2; ++ni)                                        \
            b[ni] = *(const bf16x8*)&Bs[buf][(((wn + ni*16 + fm) << 3) + (kq ^ fm7)) << 3]; \
        _Pragma("unroll")                                                     \
        for (int mi = 0; mi < 4; ++mi)                                        \
            _Pragma("unroll")                                                 \
            for (int ni = 0; ni < 2; ++ni)                                    \
                acc[mi][ni] = __builtin_amdgcn_mfma_f32_16x16x32_bf16(        \
                    a[mi], b[ni], acc[mi][ni], 0, 0, 0);                      \
    }                                                                         \
} while (0)

    STAGE(0, 0);
    __syncthreads();                          // drain prologue stage
    int cur = 0;
    for (int t = 0; t < 15; ++t) {
        STAGE(cur ^ 1, (t + 1) * 64);         // prefetch next K-tile (other buffer)
        COMPUTE(cur);                         // MFMA on current tile overlaps the loads
        __syncthreads();                      // one barrier/K-step
        cur ^= 1;
    }
    COMPUTE(cur);                             // last tile, nothing left to stage

    const int cm = (lane >> 4) * 4;   // C/D: col = lane&15, row = (lane>>4)*4 + reg
#pragma unroll
    for (int ni = 0; ni < 2; ++ni) {
        const int c = col0 + wn + ni * 16 + fm;
        const float bv = bias[c];
#pragma unroll
        for (int mi = 0; mi < 4; ++mi) {
#pragma unroll
            for (int r = 0; r < 4; ++r) {
                const int row = row0 + wm + mi * 16 + cm + r;
                H[(size_t)row * OUT_F + c] = f2bf(acc[mi][ni][r] + bv);
            }
        }
    }
#undef STAGE
#undef COMPUTE
}

// ---- dedup: wave per node -> compacted unique-neighbor list (ucol, ucnt) ----
__global__ __launch_bounds__(256) void dedup(const int* __restrict__ dg,
                                             const int* __restrict__ col,
                                             int* __restrict__ ucol,
                                             int* __restrict__ ucnt) {
    __shared__ int nbr[4][MAX_DEG];
    __shared__ int wcnt[4];
    const int wave = threadIdx.x >> 6;
    const int lane = threadIdx.x & 63;
    const int v    = blockIdx.x * 4 + wave;
    int d = dg[v];
    if (d > MAX_DEG) d = MAX_DEG;

    if (lane == 0) wcnt[wave] = 0;
    int id0 = -1, id1 = -1;
    if (lane < d)      { id0 = col[v * STRIDE + lane];      nbr[wave][lane]      = id0; }
    if (64 + lane < d) { id1 = col[v * STRIDE + 64 + lane]; nbr[wave][64 + lane] = id1; }
    __builtin_amdgcn_wave_barrier();   // wave-synchronous LDS hand-off

    // keep entry i iff no j<i equals it (no early exit -> LDS reads pipeline)
    bool k0 = (lane < d);
    const int lim0 = k0 ? lane : 0;
    for (int j = 0; j < lim0; ++j) k0 = k0 & (nbr[wave][j] != id0);
    bool k1 = (64 + lane < d);
    const int lim1 = k1 ? (64 + lane) : 0;
    for (int j = 0; j < lim1; ++j) k1 = k1 & (nbr[wave][j] != id1);
    if (k0) ucol[v * STRIDE + atomicAdd(&wcnt[wave], 1)] = id0;
    if (k1) ucol[v * STRIDE + atomicAdd(&wcnt[wave], 1)] = id1;
    __builtin_amdgcn_wave_barrier();
    if (lane == 0) ucnt[v] = wcnt[wave];
}

// ---- aggregate: wave per (node, feature-quarter); 16 rows in flight ----
__global__ __launch_bounds__(256, 8) void aggregate(const unsigned short* __restrict__ H,
                                                    const int* __restrict__ ucnt,
                                                    const int* __restrict__ ucol,
                                                    float* __restrict__ out) {
    const int wave = threadIdx.x >> 6;
    const int lane = threadIdx.x & 63;
    const int bid  = blockIdx.x;
    const int q    = bid & 3;                 // feature quarter
    const int v    = (bid >> 2) * 4 + wave;   // node (bijective over 8192 blocks)
    const int n    = ucnt[v];
    const int* uq  = ucol + v * STRIDE;
    const unsigned short* Hq = H + q * 128 + lane * 2;

    float a0 = 0.f, a1 = 0.f;
    int e = 0;
    for (; e + 16 <= n; e += 16) {            // 16 rows in flight
        unsigned h[16];
#pragma unroll
        for (int t = 0; t < 16; ++t)
            h[t] = *(const unsigned*)&Hq[(size_t)uq[e + t] * OUT_F];
#pragma unroll
        for (int t = 0; t < 16; ++t) { a0 += bflo(h[t]); a1 += bfhi(h[t]); }
    }
    for (; e + 4 <= n; e += 4) {
        unsigned h[4];
#pragma unroll
        for (int t = 0; t < 4; ++t)
            h[t] = *(const unsigned*)&Hq[(size_t)uq[e + t] * OUT_F];
#pragma unroll
        for (int t = 0; t < 4; ++t) { a0 += bflo(h[t]); a1 += bfhi(h[t]); }
    }
    for (; e < n; ++e) {
        unsigned h = *(const unsigned*)&Hq[(size_t)uq[e] * OUT_F];
        a0 += bflo(h); a1 += bfhi(h);
    }
    f32x2 o = {fmaxf(a0, 0.f), fmaxf(a1, 0.f)};
    __builtin_nontemporal_store(o, (f32x2*)&out[(size_t)v * OUT_F + q * 128 + lane * 2]);
}

extern "C" void kernel_launch(void* const* d_in, const int* in_sizes, int n_in,
                              void* d_out, int out_size, void* d_ws, size_t ws_size,
                              hipStream_t stream) {
    const float* x  = (const float*)d_in[0];
    const float* W  = (const float*)d_in[1];
    const float* b  = (const float*)d_in[2];
    const int*   ei = (const int*)d_in[3];      // [2, N_EDGES]: src then dst
    float* out = (float*)d_out;

    char* ws = (char*)d_ws;
    unsigned short* H    = (unsigned short*)(ws + HID_OFF);
    unsigned short* Wb   = (unsigned short*)(ws + WB_OFF);
    int*            deg  = (int*)(ws + DEG_OFF);
    int*            col  = (int*)(ws + COL_OFF);
    int*            ucnt = (int*)(ws + UCNT_OFF);
    int*            ucol = (int*)(ws + UCOL_OFF);

    // 1) convert W to bf16 + zero deg (tiny: 3 MB traffic)
    cvt_w<<<NW8 / 256, 256, 0, stream>>>(W, Wb, deg);

    // 2) GEMM (fp32-A staging + in-path cvt_pk) + edge scatter fused
    gemm_scatter<<<GEMM_BLOCKS + N_EDGES / 256, 256, 0, stream>>>(
        x, Wb, b, H, ei, ei + N_EDGES, deg, col);

    // 3) compact unique-neighbor lists (wave per node)
    dedup<<<N_NODES / 4, 256, 0, stream>>>(deg, col, ucol, ucnt);

    // 4) wave per (node, quarter) gather + ReLU
    aggregate<<<N_NODES * 4 / 4, 256, 0, stream>>>(H, ucnt, ucol, out);
}